// Round 18
// baseline (187.980 us; speedup 1.0000x reference)
//
#include <hip/hip_runtime.h>
#include <math.h>

// Problem constants
#define BATCH 4
#define SEQ   4096
#define DIM   2048
#define DS    64
#define NF    4096
#define NR    2048
#define NT    2048
#define NTOT  8192          // NF+NR+NT
#define TOK   16384         // BATCH*SEQ
#define KSPLIT 8
#define KS    (DIM / KSPLIT)   // 256

typedef __attribute__((ext_vector_type(8))) __bf16 bf16x8;
typedef __attribute__((ext_vector_type(4))) float  f32x4;

static __device__ __forceinline__ unsigned short f2bf(float x) {
  unsigned int u = __float_as_uint(x);
  u += 0x7fffu + ((u >> 16) & 1u);       // round-to-nearest-even
  return (unsigned short)(u >> 16);
}
static __device__ __forceinline__ float bf2f(unsigned int lo16) {
  return __uint_as_float(lo16 << 16);
}

// split 8 f32 into hi/lo bf16x8
static __device__ __forceinline__ void split8(const float4& a, const float4& b,
                                              bf16x8& hi, bf16x8& lo) {
  float v[8] = {a.x, a.y, a.z, a.w, b.x, b.y, b.z, b.w};
  union { unsigned short u[8]; bf16x8 v8; } H, L;
#pragma unroll
  for (int i = 0; i < 8; ++i) {
    unsigned short h = f2bf(v[i]);
    H.u[i] = h;
    L.u[i] = f2bf(v[i] - bf2f(h));
  }
  hi = H.v8; lo = L.v8;
}

// ---------------------------------------------------------------------------
// P0 (merged): blocks [0,2048): normalized emb -> split bf16 (4 rows/block).
//              blocks [2048,2112): W column -> transposed split bf16.
// ---------------------------------------------------------------------------
__global__ __launch_bounds__(256) void k_prep(const float* __restrict__ emb,
                                              const float* __restrict__ W,
                                              unsigned short* __restrict__ eh,
                                              unsigned short* __restrict__ el,
                                              unsigned short* __restrict__ wth,
                                              unsigned short* __restrict__ wtl) {
  if (blockIdx.x < NTOT / 4) {
    int row  = blockIdx.x * 4 + (threadIdx.x >> 6);
    int lane = threadIdx.x & 63;
    float v  = emb[(size_t)row * DS + lane];
    float ss = v * v;
#pragma unroll
    for (int m = 32; m >= 1; m >>= 1) ss += __shfl_xor(ss, m, 64);
    float sc = 1.0f / fmaxf(sqrtf(ss), 1e-12f);
    float w  = v * sc;
    unsigned short hi = f2bf(w);
    eh[(size_t)row * DS + lane] = hi;
    el[(size_t)row * DS + lane] = f2bf(w - bf2f(hi));
  } else {
    int c = blockIdx.x - NTOT / 4;     // 0..63
#pragma unroll
    for (int it = 0; it < 8; ++it) {
      int k = threadIdx.x + it * 256;
      float v = W[(size_t)k * DS + c];
      unsigned short hi = f2bf(v);
      wth[(size_t)c * DIM + k] = hi;
      wtl[(size_t)c * DIM + k] = f2bf(v - bf2f(hi));
    }
  }
}

// ---------------------------------------------------------------------------
// K1: h-partials = x @ W  (K-split 8, f32 partial out).
// grid (TOK/128, 8), 512 thr (8 waves), wave = 16 tok x 64 col.
// W slice staged in LDS ONCE -> zero barriers in K-loop. x direct from global.
// ---------------------------------------------------------------------------
__global__ __launch_bounds__(512) void k_h(
    const float* __restrict__ x, const unsigned short* __restrict__ wth,
    const unsigned short* __restrict__ wtl, float* __restrict__ Hpart) {
  __shared__ __align__(16) unsigned short wsh[64 * KS];   // 32 KB
  __shared__ __align__(16) unsigned short wsl[64 * KS];   // 32 KB
  const int tid   = threadIdx.x;
  const int t0    = blockIdx.x * 128;
  const int kbase = blockIdx.y * KS;
  const int lane  = tid & 63, wv = tid >> 6;   // 8 waves
  const int fr    = lane & 15, oct = lane >> 4;

#pragma unroll
  for (int it = 0; it < 4; ++it) {
    int idx = tid + it * 512;
    int c = idx >> 5, k16 = idx & 31;
    int bo = (c * 512 + k16 * 16) ^ ((c & 7) << 4);
    size_t src = ((size_t)c * DIM + kbase) * 2 + (size_t)k16 * 16;
    *reinterpret_cast<uint4*>((char*)wsh + bo) =
        *reinterpret_cast<const uint4*>((const char*)wth + src);
    *reinterpret_cast<uint4*>((char*)wsl + bo) =
        *reinterpret_cast<const uint4*>((const char*)wtl + src);
  }
  __syncthreads();

  const float* xp = x + (size_t)(t0 + wv * 16 + fr) * DIM + kbase + oct * 8;

  f32x4 acc[4];
#pragma unroll
  for (int j = 0; j < 4; ++j) acc[j] = (f32x4)0.0f;

  float4 xa = *reinterpret_cast<const float4*>(xp);
  float4 xb = *reinterpret_cast<const float4*>(xp + 4);

#pragma unroll
  for (int s = 0; s < KS / 32; ++s) {     // 8 steps, no barriers
    bf16x8 ah, al;
    split8(xa, xb, ah, al);
    if (s + 1 < KS / 32) {
      xa = *reinterpret_cast<const float4*>(xp + (s + 1) * 32);
      xb = *reinterpret_cast<const float4*>(xp + (s + 1) * 32 + 4);
    }
#pragma unroll
    for (int j = 0; j < 4; ++j) {
      int col = j * 16 + fr;
      int bo = (col * 512 + s * 64 + oct * 16) ^ ((col & 7) << 4);
      bf16x8 bh = *reinterpret_cast<const bf16x8*>((const char*)wsh + bo);
      bf16x8 bl = *reinterpret_cast<const bf16x8*>((const char*)wsl + bo);
      acc[j] = __builtin_amdgcn_mfma_f32_16x16x32_bf16(ah, bh, acc[j], 0, 0, 0);
      acc[j] = __builtin_amdgcn_mfma_f32_16x16x32_bf16(ah, bl, acc[j], 0, 0, 0);
      acc[j] = __builtin_amdgcn_mfma_f32_16x16x32_bf16(al, bh, acc[j], 0, 0, 0);
    }
  }

  float* op = Hpart + (size_t)blockIdx.y * TOK * DS;
#pragma unroll
  for (int j = 0; j < 4; ++j) {
    int c = j * 16 + fr;
#pragma unroll
    for (int r = 0; r < 4; ++r) {
      int t = t0 + wv * 16 + oct * 4 + r;
      op[(size_t)t * DS + c] = acc[j][r];
    }
  }
}

// ---------------------------------------------------------------------------
// K1b: combine 8 K-split partials + bias -> split bf16 h.
// ---------------------------------------------------------------------------
__global__ __launch_bounds__(256) void k_hc(const float* __restrict__ Hpart,
                                            const float* __restrict__ bias,
                                            unsigned short* __restrict__ hh,
                                            unsigned short* __restrict__ hl) {
  int idx = blockIdx.x * 256 + threadIdx.x;   // 0..TOK*16-1
  int t = idx >> 4, q = idx & 15;
  size_t o = (size_t)t * DS + q * 4;
  float4 bv = *reinterpret_cast<const float4*>(&bias[q * 4]);
  float v0 = bv.x, v1 = bv.y, v2 = bv.z, v3 = bv.w;
#pragma unroll
  for (int p = 0; p < KSPLIT; ++p) {
    float4 s = *reinterpret_cast<const float4*>(&Hpart[(size_t)p * TOK * DS + o]);
    v0 += s.x; v1 += s.y; v2 += s.z; v3 += s.w;
  }
  unsigned short h0 = f2bf(v0), h1 = f2bf(v1), h2 = f2bf(v2), h3 = f2bf(v3);
  uint2 hi; hi.x = h0 | ((unsigned)h1 << 16); hi.y = h2 | ((unsigned)h3 << 16);
  uint2 lo;
  lo.x = (unsigned)f2bf(v0 - bf2f(h0)) | ((unsigned)f2bf(v1 - bf2f(h1)) << 16);
  lo.y = (unsigned)f2bf(v2 - bf2f(h2)) | ((unsigned)f2bf(v3 - bf2f(h3)) << 16);
  *reinterpret_cast<uint2*>(&hh[o]) = hi;
  *reinterpret_cast<uint2*>(&hl[o]) = lo;
}

// ---------------------------------------------------------------------------
// K2: logits GEMM, e-resident + register-double-buffered A-fragments.
// grid (16 tg, 64 cb), 256 thr (4 waves). Block = 128 neurons x 1024 tokens.
// e chunk staged ONCE (34 KB LDS), 4 blocks/CU, ZERO barriers in token loop.
// Token loop unrolled x2 with named A/B fragment sets (static indexing,
// rule #20): loads for the next iteration issue before the current compute,
// hiding ~200-cyc L2 latency under 96 MFMAs + exp. Set A's first load
// issues before the e-staging barrier (independent of LDS).
// MODE 0: Zp[t*64+cb] = sum_n exp(logit)
// MODE 2: Bp[tg*NTOT+n] = sum_t a[sl][t] * exp(logit) (per-wave LDS acc)
// ---------------------------------------------------------------------------
template<int MODE>
__global__ __launch_bounds__(256, 4) void k_zle(
    const unsigned short* __restrict__ hh, const unsigned short* __restrict__ hl,
    const unsigned short* __restrict__ eh, const unsigned short* __restrict__ el,
    const float* __restrict__ a, float* __restrict__ Zp, float* __restrict__ Bp) {
  __shared__ __align__(16) unsigned short esh[128 * 64];   // 16 KB
  __shared__ __align__(16) unsigned short esl[128 * 64];   // 16 KB
  __shared__ float red2[512];                              // 2 KB (MODE2)
  const int tid = threadIdx.x;
  const int tg  = blockIdx.x;          // token group 0..15 (1024 tokens)
  const int cb  = blockIdx.y;          // neuron chunk 0..63 (128 n)
  const int n0  = cb * 128;

  const int lane = tid & 63;
  const int wv   = tid >> 6;
  const int fr   = lane & 15;
  const int oct  = lane >> 4;
  const int sl   = (cb < 32) ? 0 : ((cb < 48) ? 1 : 2);

  // named double-buffer fragment sets (all statically indexed)
  bf16x8 ahA[2][2], alA[2][2], ahB[2][2], alB[2][2];
  float  avA[2][4], avB[2][4];

  auto LOADF = [&](int it, bf16x8 (&ah)[2][2], bf16x8 (&al)[2][2],
                   float (&av)[2][4]) {
    const int tbase = tg * 1024 + it * 128 + wv * 32;
#pragma unroll
    for (int i = 0; i < 2; ++i)
#pragma unroll
      for (int kh = 0; kh < 2; ++kh) {
        size_t off = (size_t)(tbase + i * 16 + fr) * DS + kh * 32 + oct * 8;
        ah[i][kh] = *reinterpret_cast<const bf16x8*>(hh + off);
        al[i][kh] = *reinterpret_cast<const bf16x8*>(hl + off);
      }
    if (MODE == 2) {
#pragma unroll
      for (int i = 0; i < 2; ++i)
#pragma unroll
        for (int r = 0; r < 4; ++r)
          av[i][r] = a[(size_t)sl * TOK + tbase + i * 16 + oct * 4 + r];
    }
  };

  auto COMP = [&](int it, const bf16x8 (&ah)[2][2], const bf16x8 (&al)[2][2],
                  const float (&av)[2][4]) {
    const int tbase = tg * 1024 + it * 128 + wv * 32;
    float rs[2][4];
    if (MODE == 0) {
#pragma unroll
      for (int i = 0; i < 2; ++i)
#pragma unroll
        for (int r = 0; r < 4; ++r) rs[i][r] = 0.0f;
    }

#pragma unroll 1
    for (int jq = 0; jq < 2; ++jq) {   // 2 quads of 4 neuron-cols
      f32x4 acc[2][4];
#pragma unroll
      for (int i = 0; i < 2; ++i)
#pragma unroll
        for (int j = 0; j < 4; ++j) acc[i][j] = (f32x4)0.0f;

#pragma unroll
      for (int j = 0; j < 4; ++j) {
        int col = (jq * 4 + j) * 16 + fr;
        bf16x8 bh[2], bl[2];
#pragma unroll
        for (int kh = 0; kh < 2; ++kh) {
          int bo = (col * 128 + (kh * 32 + oct * 8) * 2) ^ ((col & 7) << 4);
          bh[kh] = *reinterpret_cast<const bf16x8*>((const char*)esh + bo);
          bl[kh] = *reinterpret_cast<const bf16x8*>((const char*)esl + bo);
        }
#pragma unroll
        for (int i = 0; i < 2; ++i) {
#pragma unroll
          for (int kh = 0; kh < 2; ++kh) {
            acc[i][j] = __builtin_amdgcn_mfma_f32_16x16x32_bf16(ah[i][kh], bh[kh], acc[i][j], 0, 0, 0);
            acc[i][j] = __builtin_amdgcn_mfma_f32_16x16x32_bf16(ah[i][kh], bl[kh], acc[i][j], 0, 0, 0);
            acc[i][j] = __builtin_amdgcn_mfma_f32_16x16x32_bf16(al[i][kh], bh[kh], acc[i][j], 0, 0, 0);
          }
        }
      }
      // C/D layout: col = lane&15, row = oct*4 + reg [m89]

      if (MODE == 0) {
#pragma unroll
        for (int i = 0; i < 2; ++i)
#pragma unroll
          for (int j = 0; j < 4; ++j)
#pragma unroll
            for (int r = 0; r < 4; ++r) rs[i][r] += __expf(acc[i][j][r]);
      } else {
#pragma unroll
        for (int j = 0; j < 4; ++j) {
          float s = 0.0f;
#pragma unroll
          for (int i = 0; i < 2; ++i)
#pragma unroll
            for (int r = 0; r < 4; ++r)
              s = fmaf(av[i][r], __expf(acc[i][j][r]), s);
          s += __shfl_xor(s, 16, 64);
          s += __shfl_xor(s, 32, 64);
          if (oct == 0)
            red2[wv * 128 + (jq * 4 + j) * 16 + fr] += s;   // wave-private
        }
      }
    }

    if (MODE == 0) {
      // reduce over the 16 neuron-col lanes (bits 0..3)
#pragma unroll
      for (int m = 1; m < 16; m <<= 1)
#pragma unroll
        for (int i = 0; i < 2; ++i)
#pragma unroll
          for (int r = 0; r < 4; ++r) rs[i][r] += __shfl_xor(rs[i][r], m, 64);
      if (fr == 0) {
#pragma unroll
        for (int i = 0; i < 2; ++i)
#pragma unroll
          for (int r = 0; r < 4; ++r) {
            int t = tbase + i * 16 + oct * 4 + r;
            Zp[(size_t)t * 64 + cb] = rs[i][r];
          }
      }
    }
  };

  // issue iteration-0 A-fragment loads BEFORE the staging barrier
  LOADF(0, ahA, alA, avA);

  // ---- stage e chunk ONCE (pure copies, swizzled) ----
#pragma unroll
  for (int it = 0; it < 4; ++it) {
    int idx = tid + it * 256;          // 0..1023: 128 rows x 8 chunks
    int r = idx >> 3, k8 = idx & 7;
    int bo = (r * 128 + k8 * 16) ^ ((r & 7) << 4);
    *reinterpret_cast<uint4*>((char*)esh + bo) =
        *reinterpret_cast<const uint4*>((const char*)eh + (size_t)(n0 + r) * 128 + k8 * 16);
    *reinterpret_cast<uint4*>((char*)esl + bo) =
        *reinterpret_cast<const uint4*>((const char*)el + (size_t)(n0 + r) * 128 + k8 * 16);
  }
  if (MODE == 2) { red2[tid] = 0.0f; red2[256 + tid] = 0.0f; }
  __syncthreads();                     // the ONLY barrier before the reduce

#pragma unroll 1
  for (int it2 = 0; it2 < 4; ++it2) {  // 4 double-iterations, no barriers
    const int itA = it2 * 2;
    LOADF(itA + 1, ahB, alB, avB);     // prefetch B while computing A
    COMP(itA, ahA, alA, avA);
    if (itA + 2 < 8) LOADF(itA + 2, ahA, alA, avA);  // prefetch A
    COMP(itA + 1, ahB, alB, avB);
  }

  if (MODE == 2) {
    __syncthreads();
    if (tid < 128) {
      float v = red2[tid] + red2[128 + tid] + red2[256 + tid] + red2[384 + tid];
      Bp[(size_t)tg * NTOT + n0 + tid] = v;
    }
  }
}

// ---------------------------------------------------------------------------
// K3: combine 64 Zp chunks per token into a[slice][t] = imp_t / Z_slice
// ---------------------------------------------------------------------------
__global__ __launch_bounds__(256) void k_a2(const float* __restrict__ Zp,
                                            const float* __restrict__ imp,
                                            float* __restrict__ a) {
  int t = blockIdx.x * 256 + threadIdx.x;
  const float4* zp = reinterpret_cast<const float4*>(&Zp[(size_t)t * 64]);
  float zf = 0.f, zr = 0.f, zt = 0.f;
#pragma unroll
  for (int q = 0; q < 8; ++q)  { float4 v = zp[q]; zf += (v.x + v.y) + (v.z + v.w); }
#pragma unroll
  for (int q = 8; q < 12; ++q) { float4 v = zp[q]; zr += (v.x + v.y) + (v.z + v.w); }
#pragma unroll
  for (int q = 12; q < 16; ++q){ float4 v = zp[q]; zt += (v.x + v.y) + (v.z + v.w); }
  float im = imp[t];
  a[t]           = im / zf;
  a[TOK + t]     = im / zr;
  a[2 * TOK + t] = im / zt;
}

// ---------------------------------------------------------------------------
// K5: per (batch, slice): 4-partial reduce + top-k + renorm.
// ---------------------------------------------------------------------------
__global__ __launch_bounds__(256) void k_topk(const float* __restrict__ Bp,
                                              float* __restrict__ out) {
  __shared__ float p[4096];
  __shared__ float rv[256];
  __shared__ int   ri[256];
  __shared__ float vals[8];
  __shared__ int   idxs[8];
  __shared__ float s_inv;

  const int bid = blockIdx.x;
  const int b   = bid / 3;
  const int sl  = bid % 3;
  const int off = (sl == 0) ? 0 : ((sl == 1) ? NF : NF + NR);
  const int N   = (sl == 0) ? NF : NR;
  const int K   = (sl == 0) ? 8 : ((sl == 1) ? 4 : 6);
  const int tid = threadIdx.x;

  const float* src = Bp + (size_t)(b * 4) * NTOT + off;
  for (int i = tid; i < N; i += 256) {
    float v = 0.0f;
#pragma unroll
    for (int g = 0; g < 4; ++g) v += src[(size_t)g * NTOT + i];
    p[i] = v;
  }
  __syncthreads();

  for (int k = 0; k < K; ++k) {
    float bv = -2.0f;
    int bi = 1 << 30;
    for (int i = tid; i < N; i += 256) {
      float v = p[i];
      if (v > bv) { bv = v; bi = i; }
    }
    rv[tid] = bv; ri[tid] = bi;
    __syncthreads();
    for (int st = 128; st > 0; st >>= 1) {
      if (tid < st) {
        float v2 = rv[tid + st]; int i2 = ri[tid + st];
        if (v2 > rv[tid] || (v2 == rv[tid] && i2 < ri[tid])) {
          rv[tid] = v2; ri[tid] = i2;
        }
      }
      __syncthreads();
    }
    if (tid == 0) {
      vals[k] = rv[0]; idxs[k] = ri[0];
      p[ri[0]] = -1.0f;
    }
    __syncthreads();
  }

  if (tid == 0) {
    float s = 0.0f;
    for (int k = 0; k < K; ++k) s += vals[k];
    s_inv = 1.0f / (s + 1e-8f);
  }
  __syncthreads();

  float* ob = out + (size_t)b * (NF + 2 * NR + NT);
  if (sl == 0) {
    for (int i = tid; i < NF; i += 256) ob[i] = 0.0f;
  } else if (sl == 1) {
    for (int i = tid; i < NR; i += 256) { ob[NF + i] = 0.0f; ob[NF + NR + i] = 0.0f; }
  } else {
    for (int i = tid; i < NT; i += 256) ob[NF + 2 * NR + i] = 0.0f;
  }
  __syncthreads();
  if (tid < K) {
    float v = vals[tid] * s_inv;
    int ix = idxs[tid];
    if (sl == 0) {
      ob[ix] = v;
    } else if (sl == 1) {
      ob[NF + ix] = v;
      ob[NF + NR + ix] = v;
    } else {
      ob[NF + 2 * NR + ix] = v;
    }
  }
}

// ---------------------------------------------------------------------------
extern "C" void kernel_launch(void* const* d_in, const int* in_sizes, int n_in,
                              void* d_out, int out_size, void* d_ws, size_t ws_size,
                              hipStream_t stream) {
  const float* x    = (const float*)d_in[0];   // [B,S,D]
  const float* imp  = (const float*)d_in[1];   // [B,S]
  const float* W    = (const float*)d_in[2];   // [D,DS]
  const float* bias = (const float*)d_in[3];   // [DS]
  const float* emb  = (const float*)d_in[4];   // [NTOT,DS]
  float* out = (float*)d_out;

  // workspace layout
  unsigned short* eh  = (unsigned short*)d_ws;            // NTOT*64
  unsigned short* el  = eh  + (size_t)NTOT * DS;
  unsigned short* wth = el  + (size_t)NTOT * DS;          // 64*2048
  unsigned short* wtl = wth + (size_t)DS * DIM;
  unsigned short* hh  = wtl + (size_t)DS * DIM;           // TOK*64
  unsigned short* hl  = hh  + (size_t)TOK * DS;
  float* Zp     = (float*)(hl + (size_t)TOK * DS);        // TOK*64
  float* a      = Zp + (size_t)TOK * 64;                  // 3*TOK
  float* Bp     = a + 3 * (size_t)TOK;                    // 16*NTOT
  float* Hpart  = Bp + (size_t)16 * NTOT;                 // KSPLIT*TOK*64

  size_t need = (2 * (size_t)NTOT * DS + 2 * (size_t)DS * DIM +
                 2 * (size_t)TOK * DS) * sizeof(unsigned short) +
                ((size_t)TOK * 64 + 3 * (size_t)TOK + 16 * (size_t)NTOT +
                 (size_t)KSPLIT * TOK * DS) * sizeof(float);
  if (ws_size < need) return;   // ~46 MB (R2 proved ws >= 281 MB)

  k_prep<<<NTOT / 4 + DS, 256, 0, stream>>>(emb, W, eh, el, wth, wtl);
  k_h<<<dim3(TOK / 128, KSPLIT), 512, 0, stream>>>(x, wth, wtl, Hpart);
  k_hc<<<TOK * 16 / 256, 256, 0, stream>>>(Hpart, bias, hh, hl);

  k_zle<0><<<dim3(16, 64), 256, 0, stream>>>(hh, hl, eh, el, nullptr, Zp, nullptr);
  k_a2<<<TOK / 256, 256, 0, stream>>>(Zp, imp, a);
  k_zle<2><<<dim3(16, 64), 256, 0, stream>>>(hh, hl, eh, el, a, nullptr, Bp);
  k_topk<<<12, 256, 0, stream>>>(Bp, out);
}

// Round 19
// 162.137 us; speedup vs baseline: 1.1594x; 1.1594x over previous
//
#include <hip/hip_runtime.h>
#include <math.h>

// Problem constants
#define BATCH 4
#define SEQ   4096
#define DIM   2048
#define DS    64
#define NF    4096
#define NR    2048
#define NT    2048
#define NTOT  8192          // NF+NR+NT
#define TOK   16384         // BATCH*SEQ
#define KSPLIT 8
#define KS    (DIM / KSPLIT)   // 256

typedef __attribute__((ext_vector_type(8))) __bf16 bf16x8;
typedef __attribute__((ext_vector_type(4))) float  f32x4;

static __device__ __forceinline__ unsigned short f2bf(float x) {
  unsigned int u = __float_as_uint(x);
  u += 0x7fffu + ((u >> 16) & 1u);       // round-to-nearest-even
  return (unsigned short)(u >> 16);
}
static __device__ __forceinline__ float bf2f(unsigned int lo16) {
  return __uint_as_float(lo16 << 16);
}

// split 8 f32 into hi/lo bf16x8
static __device__ __forceinline__ void split8(const float4& a, const float4& b,
                                              bf16x8& hi, bf16x8& lo) {
  float v[8] = {a.x, a.y, a.z, a.w, b.x, b.y, b.z, b.w};
  union { unsigned short u[8]; bf16x8 v8; } H, L;
#pragma unroll
  for (int i = 0; i < 8; ++i) {
    unsigned short h = f2bf(v[i]);
    H.u[i] = h;
    L.u[i] = f2bf(v[i] - bf2f(h));
  }
  hi = H.v8; lo = L.v8;
}

// ---------------------------------------------------------------------------
// P0 (merged): blocks [0,2048): normalized emb -> split bf16 (4 rows/block).
//              blocks [2048,2112): W column -> transposed split bf16.
// ---------------------------------------------------------------------------
__global__ __launch_bounds__(256) void k_prep(const float* __restrict__ emb,
                                              const float* __restrict__ W,
                                              unsigned short* __restrict__ eh,
                                              unsigned short* __restrict__ el,
                                              unsigned short* __restrict__ wth,
                                              unsigned short* __restrict__ wtl) {
  if (blockIdx.x < NTOT / 4) {
    int row  = blockIdx.x * 4 + (threadIdx.x >> 6);
    int lane = threadIdx.x & 63;
    float v  = emb[(size_t)row * DS + lane];
    float ss = v * v;
#pragma unroll
    for (int m = 32; m >= 1; m >>= 1) ss += __shfl_xor(ss, m, 64);
    float sc = 1.0f / fmaxf(sqrtf(ss), 1e-12f);
    float w  = v * sc;
    unsigned short hi = f2bf(w);
    eh[(size_t)row * DS + lane] = hi;
    el[(size_t)row * DS + lane] = f2bf(w - bf2f(hi));
  } else {
    int c = blockIdx.x - NTOT / 4;     // 0..63
#pragma unroll
    for (int it = 0; it < 8; ++it) {
      int k = threadIdx.x + it * 256;
      float v = W[(size_t)k * DS + c];
      unsigned short hi = f2bf(v);
      wth[(size_t)c * DIM + k] = hi;
      wtl[(size_t)c * DIM + k] = f2bf(v - bf2f(hi));
    }
  }
}

// ---------------------------------------------------------------------------
// K1: h-partials = x @ W  (K-split 8, f32 partial out).
// grid (TOK/128, 8), 512 thr (8 waves), wave = 16 tok x 64 col.
// W slice staged in LDS ONCE -> zero barriers in K-loop. x direct from global.
// ---------------------------------------------------------------------------
__global__ __launch_bounds__(512) void k_h(
    const float* __restrict__ x, const unsigned short* __restrict__ wth,
    const unsigned short* __restrict__ wtl, float* __restrict__ Hpart) {
  __shared__ __align__(16) unsigned short wsh[64 * KS];   // 32 KB
  __shared__ __align__(16) unsigned short wsl[64 * KS];   // 32 KB
  const int tid   = threadIdx.x;
  const int t0    = blockIdx.x * 128;
  const int kbase = blockIdx.y * KS;
  const int lane  = tid & 63, wv = tid >> 6;   // 8 waves
  const int fr    = lane & 15, oct = lane >> 4;

#pragma unroll
  for (int it = 0; it < 4; ++it) {
    int idx = tid + it * 512;
    int c = idx >> 5, k16 = idx & 31;
    int bo = (c * 512 + k16 * 16) ^ ((c & 7) << 4);
    size_t src = ((size_t)c * DIM + kbase) * 2 + (size_t)k16 * 16;
    *reinterpret_cast<uint4*>((char*)wsh + bo) =
        *reinterpret_cast<const uint4*>((const char*)wth + src);
    *reinterpret_cast<uint4*>((char*)wsl + bo) =
        *reinterpret_cast<const uint4*>((const char*)wtl + src);
  }
  __syncthreads();

  const float* xp = x + (size_t)(t0 + wv * 16 + fr) * DIM + kbase + oct * 8;

  f32x4 acc[4];
#pragma unroll
  for (int j = 0; j < 4; ++j) acc[j] = (f32x4)0.0f;

  float4 xa = *reinterpret_cast<const float4*>(xp);
  float4 xb = *reinterpret_cast<const float4*>(xp + 4);

#pragma unroll
  for (int s = 0; s < KS / 32; ++s) {     // 8 steps, no barriers
    bf16x8 ah, al;
    split8(xa, xb, ah, al);
    if (s + 1 < KS / 32) {
      xa = *reinterpret_cast<const float4*>(xp + (s + 1) * 32);
      xb = *reinterpret_cast<const float4*>(xp + (s + 1) * 32 + 4);
    }
#pragma unroll
    for (int j = 0; j < 4; ++j) {
      int col = j * 16 + fr;
      int bo = (col * 512 + s * 64 + oct * 16) ^ ((col & 7) << 4);
      bf16x8 bh = *reinterpret_cast<const bf16x8*>((const char*)wsh + bo);
      bf16x8 bl = *reinterpret_cast<const bf16x8*>((const char*)wsl + bo);
      acc[j] = __builtin_amdgcn_mfma_f32_16x16x32_bf16(ah, bh, acc[j], 0, 0, 0);
      acc[j] = __builtin_amdgcn_mfma_f32_16x16x32_bf16(ah, bl, acc[j], 0, 0, 0);
      acc[j] = __builtin_amdgcn_mfma_f32_16x16x32_bf16(al, bh, acc[j], 0, 0, 0);
    }
  }

  float* op = Hpart + (size_t)blockIdx.y * TOK * DS;
#pragma unroll
  for (int j = 0; j < 4; ++j) {
    int c = j * 16 + fr;
#pragma unroll
    for (int r = 0; r < 4; ++r) {
      int t = t0 + wv * 16 + oct * 4 + r;
      op[(size_t)t * DS + c] = acc[j][r];
    }
  }
}

// ---------------------------------------------------------------------------
// K1b: combine 8 K-split partials + bias -> split bf16 h.
// ---------------------------------------------------------------------------
__global__ __launch_bounds__(256) void k_hc(const float* __restrict__ Hpart,
                                            const float* __restrict__ bias,
                                            unsigned short* __restrict__ hh,
                                            unsigned short* __restrict__ hl) {
  int idx = blockIdx.x * 256 + threadIdx.x;   // 0..TOK*16-1
  int t = idx >> 4, q = idx & 15;
  size_t o = (size_t)t * DS + q * 4;
  float4 bv = *reinterpret_cast<const float4*>(&bias[q * 4]);
  float v0 = bv.x, v1 = bv.y, v2 = bv.z, v3 = bv.w;
#pragma unroll
  for (int p = 0; p < KSPLIT; ++p) {
    float4 s = *reinterpret_cast<const float4*>(&Hpart[(size_t)p * TOK * DS + o]);
    v0 += s.x; v1 += s.y; v2 += s.z; v3 += s.w;
  }
  unsigned short h0 = f2bf(v0), h1 = f2bf(v1), h2 = f2bf(v2), h3 = f2bf(v3);
  uint2 hi; hi.x = h0 | ((unsigned)h1 << 16); hi.y = h2 | ((unsigned)h3 << 16);
  uint2 lo;
  lo.x = (unsigned)f2bf(v0 - bf2f(h0)) | ((unsigned)f2bf(v1 - bf2f(h1)) << 16);
  lo.y = (unsigned)f2bf(v2 - bf2f(h2)) | ((unsigned)f2bf(v3 - bf2f(h3)) << 16);
  *reinterpret_cast<uint2*>(&hh[o]) = hi;
  *reinterpret_cast<uint2*>(&hl[o]) = lo;
}

// ---------------------------------------------------------------------------
// K2: logits GEMM, e-resident (R14/R17-proven).
// grid (16 tg, 64 cb), 256 thr (4 waves). Block = 128 neurons x 1024 tokens.
// e chunk staged ONCE (34 KB LDS) -> 4 blocks/CU at launch_bounds(256,4);
// ZERO barriers across the 8 token-iterations. A-fragments direct from
// L2-resident hh/hl. unroll-1 on it/jq loops stops software-pipelining
// (spill prevention); MODE2 pools into per-wave-private LDS.
// MODE 0: Zp[t*64+cb] = sum_n exp(logit)
// MODE 2: Bp[tg*NTOT+n] = sum_t a[sl][t] * exp(logit)
// ---------------------------------------------------------------------------
template<int MODE>
__global__ __launch_bounds__(256, 4) void k_zle(
    const unsigned short* __restrict__ hh, const unsigned short* __restrict__ hl,
    const unsigned short* __restrict__ eh, const unsigned short* __restrict__ el,
    const float* __restrict__ a, float* __restrict__ Zp, float* __restrict__ Bp) {
  __shared__ __align__(16) unsigned short esh[128 * 64];   // 16 KB
  __shared__ __align__(16) unsigned short esl[128 * 64];   // 16 KB
  __shared__ float red2[512];                              // 2 KB (MODE2)
  const int tid = threadIdx.x;
  const int tg  = blockIdx.x;          // token group 0..15 (1024 tokens)
  const int cb  = blockIdx.y;          // neuron chunk 0..63 (128 n)
  const int n0  = cb * 128;

  // ---- stage e chunk ONCE (pure copies, swizzled) ----
#pragma unroll
  for (int it = 0; it < 4; ++it) {
    int idx = tid + it * 256;          // 0..1023: 128 rows x 8 chunks
    int r = idx >> 3, k8 = idx & 7;
    int bo = (r * 128 + k8 * 16) ^ ((r & 7) << 4);
    *reinterpret_cast<uint4*>((char*)esh + bo) =
        *reinterpret_cast<const uint4*>((const char*)eh + (size_t)(n0 + r) * 128 + k8 * 16);
    *reinterpret_cast<uint4*>((char*)esl + bo) =
        *reinterpret_cast<const uint4*>((const char*)el + (size_t)(n0 + r) * 128 + k8 * 16);
  }
  if (MODE == 2) { red2[tid] = 0.0f; red2[256 + tid] = 0.0f; }
  __syncthreads();                     // the ONLY barrier before the reduce

  const int lane = tid & 63;
  const int wv   = tid >> 6;
  const int fr   = lane & 15;
  const int oct  = lane >> 4;
  const int sl   = (cb < 32) ? 0 : ((cb < 48) ? 1 : 2);

#pragma unroll 1
  for (int it = 0; it < 8; ++it) {     // 8 x 128-token iterations, no barriers
    const int tbase = tg * 1024 + it * 128 + wv * 32;

    // A fragments direct from global (L2-resident)
    bf16x8 ah[2][2], al[2][2];
#pragma unroll
    for (int i = 0; i < 2; ++i)
#pragma unroll
      for (int kh = 0; kh < 2; ++kh) {
        size_t off = (size_t)(tbase + i * 16 + fr) * DS + kh * 32 + oct * 8;
        ah[i][kh] = *reinterpret_cast<const bf16x8*>(hh + off);
        al[i][kh] = *reinterpret_cast<const bf16x8*>(hl + off);
      }

    float av[2][4];
    if (MODE == 2) {
#pragma unroll
      for (int i = 0; i < 2; ++i)
#pragma unroll
        for (int r = 0; r < 4; ++r)
          av[i][r] = a[(size_t)sl * TOK + tbase + i * 16 + oct * 4 + r];
    }
    float rs[2][4];
    if (MODE == 0) {
#pragma unroll
      for (int i = 0; i < 2; ++i)
#pragma unroll
        for (int r = 0; r < 4; ++r) rs[i][r] = 0.0f;
    }

#pragma unroll 1
    for (int jq = 0; jq < 2; ++jq) {   // 2 quads of 4 neuron-cols
      f32x4 acc[2][4];
#pragma unroll
      for (int i = 0; i < 2; ++i)
#pragma unroll
        for (int j = 0; j < 4; ++j) acc[i][j] = (f32x4)0.0f;

#pragma unroll
      for (int j = 0; j < 4; ++j) {
        int col = (jq * 4 + j) * 16 + fr;
        bf16x8 bh[2], bl[2];
#pragma unroll
        for (int kh = 0; kh < 2; ++kh) {
          int bo = (col * 128 + (kh * 32 + oct * 8) * 2) ^ ((col & 7) << 4);
          bh[kh] = *reinterpret_cast<const bf16x8*>((const char*)esh + bo);
          bl[kh] = *reinterpret_cast<const bf16x8*>((const char*)esl + bo);
        }
#pragma unroll
        for (int i = 0; i < 2; ++i) {
#pragma unroll
          for (int kh = 0; kh < 2; ++kh) {
            acc[i][j] = __builtin_amdgcn_mfma_f32_16x16x32_bf16(ah[i][kh], bh[kh], acc[i][j], 0, 0, 0);
            acc[i][j] = __builtin_amdgcn_mfma_f32_16x16x32_bf16(ah[i][kh], bl[kh], acc[i][j], 0, 0, 0);
            acc[i][j] = __builtin_amdgcn_mfma_f32_16x16x32_bf16(al[i][kh], bh[kh], acc[i][j], 0, 0, 0);
          }
        }
      }
      // C/D layout: col = lane&15, row = oct*4 + reg [m89]

      if (MODE == 0) {
#pragma unroll
        for (int i = 0; i < 2; ++i)
#pragma unroll
          for (int j = 0; j < 4; ++j)
#pragma unroll
            for (int r = 0; r < 4; ++r) rs[i][r] += __expf(acc[i][j][r]);
      } else {
#pragma unroll
        for (int j = 0; j < 4; ++j) {
          float s = 0.0f;
#pragma unroll
          for (int i = 0; i < 2; ++i)
#pragma unroll
            for (int r = 0; r < 4; ++r)
              s = fmaf(av[i][r], __expf(acc[i][j][r]), s);
          s += __shfl_xor(s, 16, 64);
          s += __shfl_xor(s, 32, 64);
          if (oct == 0)
            red2[wv * 128 + (jq * 4 + j) * 16 + fr] += s;   // wave-private
        }
      }
    }

    if (MODE == 0) {
      // reduce over the 16 neuron-col lanes (bits 0..3)
#pragma unroll
      for (int m = 1; m < 16; m <<= 1)
#pragma unroll
        for (int i = 0; i < 2; ++i)
#pragma unroll
          for (int r = 0; r < 4; ++r) rs[i][r] += __shfl_xor(rs[i][r], m, 64);
      if (fr == 0) {
#pragma unroll
        for (int i = 0; i < 2; ++i)
#pragma unroll
          for (int r = 0; r < 4; ++r) {
            int t = tbase + i * 16 + oct * 4 + r;
            Zp[(size_t)t * 64 + cb] = rs[i][r];
          }
      }
    }
  }

  if (MODE == 2) {
    __syncthreads();
    if (tid < 128) {
      float v = red2[tid] + red2[128 + tid] + red2[256 + tid] + red2[384 + tid];
      Bp[(size_t)tg * NTOT + n0 + tid] = v;
    }
  }
}

// ---------------------------------------------------------------------------
// K3: combine 64 Zp chunks per token into a[slice][t] = imp_t / Z_slice
// ---------------------------------------------------------------------------
__global__ __launch_bounds__(256) void k_a2(const float* __restrict__ Zp,
                                            const float* __restrict__ imp,
                                            float* __restrict__ a) {
  int t = blockIdx.x * 256 + threadIdx.x;
  const float4* zp = reinterpret_cast<const float4*>(&Zp[(size_t)t * 64]);
  float zf = 0.f, zr = 0.f, zt = 0.f;
#pragma unroll
  for (int q = 0; q < 8; ++q)  { float4 v = zp[q]; zf += (v.x + v.y) + (v.z + v.w); }
#pragma unroll
  for (int q = 8; q < 12; ++q) { float4 v = zp[q]; zr += (v.x + v.y) + (v.z + v.w); }
#pragma unroll
  for (int q = 12; q < 16; ++q){ float4 v = zp[q]; zt += (v.x + v.y) + (v.z + v.w); }
  float im = imp[t];
  a[t]           = im / zf;
  a[TOK + t]     = im / zr;
  a[2 * TOK + t] = im / zt;
}

// ---------------------------------------------------------------------------
// K5: per (batch, slice): 4-partial reduce + top-k + renorm.
// ---------------------------------------------------------------------------
__global__ __launch_bounds__(256) void k_topk(const float* __restrict__ Bp,
                                              float* __restrict__ out) {
  __shared__ float p[4096];
  __shared__ float rv[256];
  __shared__ int   ri[256];
  __shared__ float vals[8];
  __shared__ int   idxs[8];
  __shared__ float s_inv;

  const int bid = blockIdx.x;
  const int b   = bid / 3;
  const int sl  = bid % 3;
  const int off = (sl == 0) ? 0 : ((sl == 1) ? NF : NF + NR);
  const int N   = (sl == 0) ? NF : NR;
  const int K   = (sl == 0) ? 8 : ((sl == 1) ? 4 : 6);
  const int tid = threadIdx.x;

  const float* src = Bp + (size_t)(b * 4) * NTOT + off;
  for (int i = tid; i < N; i += 256) {
    float v = 0.0f;
#pragma unroll
    for (int g = 0; g < 4; ++g) v += src[(size_t)g * NTOT + i];
    p[i] = v;
  }
  __syncthreads();

  for (int k = 0; k < K; ++k) {
    float bv = -2.0f;
    int bi = 1 << 30;
    for (int i = tid; i < N; i += 256) {
      float v = p[i];
      if (v > bv) { bv = v; bi = i; }
    }
    rv[tid] = bv; ri[tid] = bi;
    __syncthreads();
    for (int st = 128; st > 0; st >>= 1) {
      if (tid < st) {
        float v2 = rv[tid + st]; int i2 = ri[tid + st];
        if (v2 > rv[tid] || (v2 == rv[tid] && i2 < ri[tid])) {
          rv[tid] = v2; ri[tid] = i2;
        }
      }
      __syncthreads();
    }
    if (tid == 0) {
      vals[k] = rv[0]; idxs[k] = ri[0];
      p[ri[0]] = -1.0f;
    }
    __syncthreads();
  }

  if (tid == 0) {
    float s = 0.0f;
    for (int k = 0; k < K; ++k) s += vals[k];
    s_inv = 1.0f / (s + 1e-8f);
  }
  __syncthreads();

  float* ob = out + (size_t)b * (NF + 2 * NR + NT);
  if (sl == 0) {
    for (int i = tid; i < NF; i += 256) ob[i] = 0.0f;
  } else if (sl == 1) {
    for (int i = tid; i < NR; i += 256) { ob[NF + i] = 0.0f; ob[NF + NR + i] = 0.0f; }
  } else {
    for (int i = tid; i < NT; i += 256) ob[NF + 2 * NR + i] = 0.0f;
  }
  __syncthreads();
  if (tid < K) {
    float v = vals[tid] * s_inv;
    int ix = idxs[tid];
    if (sl == 0) {
      ob[ix] = v;
    } else if (sl == 1) {
      ob[NF + ix] = v;
      ob[NF + NR + ix] = v;
    } else {
      ob[NF + 2 * NR + ix] = v;
    }
  }
}

// ---------------------------------------------------------------------------
extern "C" void kernel_launch(void* const* d_in, const int* in_sizes, int n_in,
                              void* d_out, int out_size, void* d_ws, size_t ws_size,
                              hipStream_t stream) {
  const float* x    = (const float*)d_in[0];   // [B,S,D]
  const float* imp  = (const float*)d_in[1];   // [B,S]
  const float* W    = (const float*)d_in[2];   // [D,DS]
  const float* bias = (const float*)d_in[3];   // [DS]
  const float* emb  = (const float*)d_in[4];   // [NTOT,DS]
  float* out = (float*)d_out;

  // workspace layout
  unsigned short* eh  = (unsigned short*)d_ws;            // NTOT*64
  unsigned short* el  = eh  + (size_t)NTOT * DS;
  unsigned short* wth = el  + (size_t)NTOT * DS;          // 64*2048
  unsigned short* wtl = wth + (size_t)DS * DIM;
  unsigned short* hh  = wtl + (size_t)DS * DIM;           // TOK*64
  unsigned short* hl  = hh  + (size_t)TOK * DS;
  float* Zp     = (float*)(hl + (size_t)TOK * DS);        // TOK*64
  float* a      = Zp + (size_t)TOK * 64;                  // 3*TOK
  float* Bp     = a + 3 * (size_t)TOK;                    // 16*NTOT
  float* Hpart  = Bp + (size_t)16 * NTOT;                 // KSPLIT*TOK*64

  size_t need = (2 * (size_t)NTOT * DS + 2 * (size_t)DS * DIM +
                 2 * (size_t)TOK * DS) * sizeof(unsigned short) +
                ((size_t)TOK * 64 + 3 * (size_t)TOK + 16 * (size_t)NTOT +
                 (size_t)KSPLIT * TOK * DS) * sizeof(float);
  if (ws_size < need) return;   // ~46 MB (R2 proved ws >= 281 MB)

  k_prep<<<NTOT / 4 + DS, 256, 0, stream>>>(emb, W, eh, el, wth, wtl);
  k_h<<<dim3(TOK / 128, KSPLIT), 512, 0, stream>>>(x, wth, wtl, Hpart);
  k_hc<<<TOK * 16 / 256, 256, 0, stream>>>(Hpart, bias, hh, hl);

  k_zle<0><<<dim3(16, 64), 256, 0, stream>>>(hh, hl, eh, el, nullptr, Zp, nullptr);
  k_a2<<<TOK / 256, 256, 0, stream>>>(Zp, imp, a);
  k_zle<2><<<dim3(16, 64), 256, 0, stream>>>(hh, hl, eh, el, a, nullptr, Bp);
  k_topk<<<12, 256, 0, stream>>>(Bp, out);
}